// Round 1
// 565.753 us; speedup vs baseline: 1.0536x; 1.0536x over previous
//
#include <hip/hip_runtime.h>

typedef __attribute__((ext_vector_type(8))) short  short8;
typedef __attribute__((ext_vector_type(4))) float  floatx4;
typedef __attribute__((ext_vector_type(2))) unsigned int uint2v;

#define NS 8   // L splits in attention

__device__ __forceinline__ unsigned short f2b(float f) {
  union { float f; unsigned u; } c; c.f = f;
  unsigned r = c.u + 0x7FFFu + ((c.u >> 16) & 1u);
  return (unsigned short)(r >> 16);
}

__device__ __forceinline__ float b2f(unsigned short u) {
  union { unsigned u; float f; } c; c.u = (unsigned)u << 16;
  return c.f;
}

__device__ __forceinline__ unsigned cvt_pk_bf16(float a, float b) {
  unsigned r;
  asm("v_cvt_pk_bf16_f32 %0, %1, %2" : "=v"(r) : "v"(a), "v"(b));
  return r;
}

__device__ __forceinline__ void async_copy16(const void* g, void* l) {
  __builtin_amdgcn_global_load_lds(
      (const __attribute__((address_space(1))) void*)g,
      (__attribute__((address_space(3))) void*)l, 16, 0, 0);
}

// ---------------- LayerNorm + bf16 cast: one block per row of 1024 ----------
__global__ __launch_bounds__(256) void ln_bf16_kernel(
    const float* __restrict__ src, const float* __restrict__ w,
    const float* __restrict__ bias, unsigned short* __restrict__ dst) {
  const size_t row = blockIdx.x;
  const int t = threadIdx.x;
  const float4 v = *(const float4*)&src[row * 1024 + t * 4];
  float s = v.x + v.y + v.z + v.w;
  float q = v.x * v.x + v.y * v.y + v.z * v.z + v.w * v.w;
#pragma unroll
  for (int m = 32; m >= 1; m >>= 1) {
    s += __shfl_xor(s, m, 64);
    q += __shfl_xor(q, m, 64);
  }
  __shared__ float ss[4], sq[4];
  if ((t & 63) == 0) { ss[t >> 6] = s; sq[t >> 6] = q; }
  __syncthreads();
  s = ss[0] + ss[1] + ss[2] + ss[3];
  q = sq[0] + sq[1] + sq[2] + sq[3];
  const float mu = s * (1.f / 1024.f);
  const float var = q * (1.f / 1024.f) - mu * mu;
  const float rs = rsqrtf(var + 1e-5f);
  const float4 wv = *(const float4*)&w[t * 4];
  const float4 bv = *(const float4*)&bias[t * 4];
  ushort4 o;
  o.x = f2b((v.x - mu) * rs * wv.x + bv.x);
  o.y = f2b((v.y - mu) * rs * wv.y + bv.y);
  o.z = f2b((v.z - mu) * rs * wv.z + bv.z);
  o.w = f2b((v.w - mu) * rs * wv.w + bv.w);
  *(ushort4*)&dst[row * 1024 + t * 4] = o;
}

// ---------------- f32 -> bf16 convert (weights) ------------------------------
__global__ __launch_bounds__(256) void conv_bf16_kernel(
    const float* __restrict__ src, unsigned short* __restrict__ dst) {
  const size_t i = (size_t)blockIdx.x * 256 + threadIdx.x;
  const float4 v = ((const float4*)src)[i];
  ushort4 o;
  o.x = f2b(v.x); o.y = f2b(v.y); o.z = f2b(v.z); o.w = f2b(v.w);
  ((ushort4*)dst)[i] = o;
}

// ---------------- V transpose: Vbf[bh][d][4096] = bf16(x[b][k][h*64+d]) -----
__global__ __launch_bounds__(256) void vtrans_kernel(
    const float* __restrict__ x, unsigned short* __restrict__ Vbf) {
  const int bh = blockIdx.x, kb = blockIdx.y;
  const int b = bh >> 4, h = bh & 15;
  const int t = threadIdx.x;
  const int d = t >> 2, kc = t & 3;
  const float* xp = x + (size_t)(b * 4096 + kb * 256) * 1024 + h * 64 + d;
  unsigned short* vp = Vbf + ((size_t)bh * 64 + d) * 4096 + kb * 256;
#pragma unroll
  for (int c = 0; c < 8; c++) {
    const int kk = c * 32 + kc * 8;
    short8 o;
#pragma unroll
    for (int j = 0; j < 8; j++)
      o[j] = (short)f2b(xp[(size_t)(kk + j) * 1024]);
    *(short8*)&vp[kk] = o;
  }
}

// ---------------- GEMM: out[m,n] = clip(A[m,:]·W[n,:] + bias[n]), bf16 ------
__global__ __launch_bounds__(256) void gemm_bt_kernel(
    const unsigned short* __restrict__ A, const unsigned short* __restrict__ W,
    const float* __restrict__ bias, unsigned short* __restrict__ out, int M) {
  __shared__ __align__(16) unsigned short As[128 * 64];
  __shared__ __align__(16) unsigned short Bs[128 * 64];
  const int tid = threadIdx.x;
  const int wave = tid >> 6, lane = tid & 63;
  const int quad = lane >> 4, l16 = lane & 15;
  const size_t m0 = (size_t)blockIdx.x * 128;
  const int n0 = blockIdx.y * 128;
  const int wm = (wave >> 1) * 64, wn = (wave & 1) * 64;
  const int r8 = lane >> 3, cvv = lane & 7;
  const int csrc = cvv ^ r8;

  floatx4 acc[4][4];
#pragma unroll
  for (int i = 0; i < 4; i++)
#pragma unroll
    for (int j = 0; j < 4; j++) acc[i][j] = (floatx4){0.f, 0.f, 0.f, 0.f};

  const unsigned short* gA = A + (m0 + wave * 32 + r8) * 1024 + csrc * 8;
  const unsigned short* gB = W + ((size_t)(n0 + wave * 32 + r8)) * 1024 + csrc * 8;

  for (int k0 = 0; k0 < 1024; k0 += 64) {
    __syncthreads();
#pragma unroll
    for (int it = 0; it < 4; ++it) {
      async_copy16(gA + (size_t)it * 8 * 1024 + k0, &As[(wave * 4 + it) * 512]);
      async_copy16(gB + (size_t)it * 8 * 1024 + k0, &Bs[(wave * 4 + it) * 512]);
    }
    __syncthreads();
#pragma unroll
    for (int kh = 0; kh < 2; ++kh) {
      short8 af[4], bf[4];
#pragma unroll
      for (int mi = 0; mi < 4; mi++) {
        int row = wm + mi * 16 + l16;
        af[mi] = *(const short8*)&As[row * 64 + (((kh * 4 + quad) ^ (row & 7)) * 8)];
      }
#pragma unroll
      for (int ni = 0; ni < 4; ni++) {
        int row = wn + ni * 16 + l16;
        bf[ni] = *(const short8*)&Bs[row * 64 + (((kh * 4 + quad) ^ (row & 7)) * 8)];
      }
#pragma unroll
      for (int mi = 0; mi < 4; mi++)
#pragma unroll
        for (int ni = 0; ni < 4; ni++)
          acc[mi][ni] = __builtin_amdgcn_mfma_f32_16x16x32_bf16(af[mi], bf[ni], acc[mi][ni], 0, 0, 0);
    }
  }
#pragma unroll
  for (int ni = 0; ni < 4; ni++) {
    int n = n0 + wn + ni * 16 + l16;
    float bv = bias[n];
#pragma unroll
    for (int mi = 0; mi < 4; mi++)
#pragma unroll
      for (int p = 0; p < 4; p++) {
        size_t m = m0 + wm + mi * 16 + quad * 4 + p;
        float v = acc[mi][ni][p] + bv;
        v = fminf(10.f, fmaxf(-10.f, v));
        out[m * 1024 + n] = f2b(v);
      }
  }
}

// ---------------- Attention: S^T orientation + packed P staging + T14 -------
// grid (128 = b*h, NS). QK^T computed transposed (mfma(K,Q)) so each lane
// holds 4 consecutive-kk P values -> 2x cvt_pk_bf16 + one ds_write_b64 per
// (mi,ni) instead of 64 scalar f2b+ds_write_b16. K/V staging is reg-staged
// with next-tile prefetch issued before compute (HBM latency hides under
// QK/softmax/PV). PV read side (layout+swizzle) is unchanged.
__global__ __launch_bounds__(256) void attn_kernel(
    const unsigned short* __restrict__ Qp,   // [2048,1024] bf16
    const unsigned short* __restrict__ Kp,   // [32768,1024] bf16
    const unsigned short* __restrict__ Vbf,  // [128][64][4096] bf16
    unsigned short* __restrict__ Onum,       // [128][NS][256][64] bf16
    float* __restrict__ lpart) {             // [128][NS][256]
  const int bh = blockIdx.x, split = blockIdx.y;
  const int b = bh >> 4, h = bh & 15;
  const int tid = threadIdx.x, wave = tid >> 6, lane = tid & 63;
  const int quad = lane >> 4, l16 = lane & 15;
  const int r8 = lane >> 3, cvv = lane & 7, csrc = cvv ^ r8;

  __shared__ __align__(16) unsigned short Ks[64 * 64];     // [kk][dk] swizzled
  __shared__ __align__(16) unsigned short Vs[64 * 64];     // [d][kk] swizzled
  __shared__ __align__(16) unsigned short Pw[4][64 * 64];  // wave-private

  short8 qf[4][2];
#pragma unroll
  for (int mi = 0; mi < 4; mi++)
#pragma unroll
    for (int kh = 0; kh < 2; kh++)
      qf[mi][kh] = *(const short8*)&Qp[(size_t)(b * 256 + wave * 64 + mi * 16 + l16) * 1024 +
                                       h * 64 + kh * 32 + quad * 8];

  floatx4 oacc[4][4];
  floatx4 lacc[4];
#pragma unroll
  for (int i = 0; i < 4; i++) {
    lacc[i] = (floatx4){0.f, 0.f, 0.f, 0.f};
#pragma unroll
    for (int j = 0; j < 4; j++) oacc[i][j] = (floatx4){0.f, 0.f, 0.f, 0.f};
  }
  short8 ones;
#pragma unroll
  for (int j = 0; j < 8; j++) ones[j] = (short)0x3F80;  // bf16 1.0

  const int kbase = split * (4096 / NS);
  // staging roles: waves 0,1 -> K rows [wave*32, +32); waves 2,3 -> V rows
  const int rowbase = (wave & 1) * 32;
  const bool isK = (wave < 2);
  const unsigned short* gK = Kp + ((size_t)(b * 4096 + kbase + rowbase + r8)) * 1024 +
                             h * 64 + csrc * 8;
  const unsigned short* gV = Vbf + ((size_t)(bh * 64 + rowbase + r8)) * 4096 +
                             kbase + csrc * 8;

  const int T = 4096 / NS / 64;  // 8 tiles per split

  // prologue: prefetch tile 0 into registers
  uint4 stg[4];
  if (isK) {
#pragma unroll
    for (int it = 0; it < 4; ++it)
      stg[it] = *(const uint4*)&gK[((size_t)it * 8) * 1024];
  } else {
#pragma unroll
    for (int it = 0; it < 4; ++it)
      stg[it] = *(const uint4*)&gV[(size_t)it * 8 * 4096];
  }

  for (int t = 0; t < T; ++t) {
    __syncthreads();  // all waves done reading previous tile's LDS
    // write staged registers -> LDS (compiler inserts vmcnt wait on stg dep)
    if (isK) {
#pragma unroll
      for (int it = 0; it < 4; ++it)
        *(uint4*)((char*)Ks + (rowbase + it * 8) * 128 + lane * 16) = stg[it];
    } else {
#pragma unroll
      for (int it = 0; it < 4; ++it)
        *(uint4*)((char*)Vs + (rowbase + it * 8) * 128 + lane * 16) = stg[it];
    }
    __syncthreads();
    // issue next tile's loads now; latency hides under compute below
    if (t + 1 < T) {
      if (isK) {
#pragma unroll
        for (int it = 0; it < 4; ++it)
          stg[it] = *(const uint4*)&gK[((size_t)(t + 1) * 64 + it * 8) * 1024];
      } else {
#pragma unroll
        for (int it = 0; it < 4; ++it)
          stg[it] = *(const uint4*)&gV[(size_t)it * 8 * 4096 + (t + 1) * 64];
      }
    }

    // ---- QK^T transposed: st[mi] lane holds S^T[kk=ni*16+quad*4+p][q=mi*16+l16]
#pragma unroll
    for (int ni = 0; ni < 4; ++ni) {
      const int krow = ni * 16 + l16;
      const short8 kf0 = *(const short8*)&Ks[krow * 64 + (((0 + quad) ^ (krow & 7)) * 8)];
      const short8 kf1 = *(const short8*)&Ks[krow * 64 + (((4 + quad) ^ (krow & 7)) * 8)];
      floatx4 st[4];
#pragma unroll
      for (int mi = 0; mi < 4; ++mi) {
        st[mi] = (floatx4){0.f, 0.f, 0.f, 0.f};
        st[mi] = __builtin_amdgcn_mfma_f32_16x16x32_bf16(kf0, qf[mi][0], st[mi], 0, 0, 0);
        st[mi] = __builtin_amdgcn_mfma_f32_16x16x32_bf16(kf1, qf[mi][1], st[mi], 0, 0, 0);
      }
      // exp2-folded softmax numerator, pack 4 consecutive kk, one b64 write
#pragma unroll
      for (int mi = 0; mi < 4; ++mi) {
        const float C = 0.18033688011112042f;  // 0.125 * log2(e)
        float e0 = exp2f(st[mi][0] * C);
        float e1 = exp2f(st[mi][1] * C);
        float e2 = exp2f(st[mi][2] * C);
        float e3 = exp2f(st[mi][3] * C);
        unsigned lo = cvt_pk_bf16(e0, e1);
        unsigned hi = cvt_pk_bf16(e2, e3);
        const int q = mi * 16 + l16;
        // kk = ni*16 + quad*4 + p : chunk = kk>>3 = 2*ni + (quad>>1),
        // within-chunk = (quad&1)*4 + p ; same swizzle convention as reads.
        const int chunk = (ni * 2 + (quad >> 1)) ^ (q & 7);
        uint2v w; w.x = lo; w.y = hi;
        *(uint2v*)&Pw[wave][q * 64 + chunk * 8 + (quad & 1) * 4] = w;
      }
    }

    // ---- PV (+ row-sum via ones column) — read side unchanged
#pragma unroll
    for (int kh = 0; kh < 2; ++kh) {
      short8 pf[4], vf[4];
#pragma unroll
      for (int ni = 0; ni < 4; ni++) {
        int row = ni * 16 + l16;
        vf[ni] = *(const short8*)&Vs[row * 64 + (((kh * 4 + quad) ^ (row & 7)) * 8)];
      }
#pragma unroll
      for (int mi = 0; mi < 4; mi++) {
        int q = mi * 16 + l16;
        pf[mi] = *(const short8*)&Pw[wave][q * 64 + (((kh * 4 + quad) ^ (q & 7)) * 8)];
      }
#pragma unroll
      for (int mi = 0; mi < 4; mi++) {
#pragma unroll
        for (int ni = 0; ni < 4; ni++)
          oacc[mi][ni] = __builtin_amdgcn_mfma_f32_16x16x32_bf16(pf[mi], vf[ni], oacc[mi][ni], 0, 0, 0);
        lacc[mi] = __builtin_amdgcn_mfma_f32_16x16x32_bf16(pf[mi], ones, lacc[mi], 0, 0, 0);
      }
    }
  }

  unsigned short* Ob = Onum + ((size_t)bh * NS + split) * 256 * 64;
#pragma unroll
  for (int mi = 0; mi < 4; mi++)
#pragma unroll
    for (int ni = 0; ni < 4; ni++)
#pragma unroll
      for (int p = 0; p < 4; p++) {
        int q = wave * 64 + mi * 16 + quad * 4 + p;
        int d = ni * 16 + l16;
        Ob[q * 64 + d] = f2b(oacc[mi][ni][p]);
      }
  if (l16 == 0) {
    float* lb = lpart + ((size_t)bh * NS + split) * 256;
#pragma unroll
    for (int mi = 0; mi < 4; mi++)
#pragma unroll
      for (int p = 0; p < 4; p++)
        lb[wave * 64 + mi * 16 + quad * 4 + p] = lacc[mi][p];
  }
}

// ---------------- reduce: ho[b, h*64+d] = mean_q( sum_s O / sum_s l ) --------
__global__ __launch_bounds__(256) void reduce_heads_kernel(
    const unsigned short* __restrict__ Onum, const float* __restrict__ lpart,
    float* __restrict__ ho) {
  const int bh = blockIdx.x;
  const int t = threadIdx.x;
  __shared__ float ls[256];
  __shared__ float red[16][64];
  float l = 0.f;
#pragma unroll
  for (int s = 0; s < NS; s++) l += lpart[((size_t)bh * NS + s) * 256 + t];
  ls[t] = l;
  __syncthreads();
  const int d4 = t & 15, qg = t >> 4;  // d = d4*4, 16 q-groups of 16
  float4 part = {0.f, 0.f, 0.f, 0.f};
  for (int qi = 0; qi < 16; ++qi) {
    int q = qg * 16 + qi;
    float4 on = {0.f, 0.f, 0.f, 0.f};
#pragma unroll
    for (int s = 0; s < NS; s++) {
      ushort4 v = *(const ushort4*)&Onum[(((size_t)bh * NS + s) * 256 + q) * 64 + d4 * 4];
      on.x += b2f(v.x); on.y += b2f(v.y); on.z += b2f(v.z); on.w += b2f(v.w);
    }
    const float rl = 1.f / ls[q];
    part.x += on.x * rl; part.y += on.y * rl;
    part.z += on.z * rl; part.w += on.w * rl;
  }
  *(float4*)&red[qg][d4 * 4] = part;
  __syncthreads();
  if (t < 64) {
    float v = 0.f;
#pragma unroll
    for (int r = 0; r < 16; ++r) v += red[r][t];
    v *= (1.f / 256.f);
    int b = bh >> 4, h = bh & 15;
    ho[b * 1024 + h * 64 + t] = v;
  }
}

// ---------------- gs[b,c] = bo[c] + sum_k Wo[c,k] * ho[b,k] ------------------
__global__ __launch_bounds__(256) void wo_proj_kernel(
    const float* __restrict__ ho, const float* __restrict__ Wo,
    const float* __restrict__ bo, float* __restrict__ gs) {
  const int b = blockIdx.x >> 2, cg = blockIdx.x & 3;
  const int t = threadIdx.x;
  __shared__ float hs[1024];
#pragma unroll
  for (int i = 0; i < 4; i++) hs[t + i * 256] = ho[b * 1024 + t + i * 256];
  __syncthreads();
  const int c = cg * 256 + t;
  const float* wrow = Wo + (size_t)c * 1024;
  float acc = bo[c];
  for (int k = 0; k < 1024; k += 4) {
    float4 w4 = *(const float4*)&wrow[k];
    acc += w4.x * hs[k] + w4.y * hs[k + 1] + w4.z * hs[k + 2] + w4.w * hs[k + 3];
  }
  gs[b * 1024 + c] = acc;
}

// ---------------- out = x + a * gs[b,:] --------------------------------------
__global__ __launch_bounds__(256) void final_add_kernel(
    const float* __restrict__ x, const float* __restrict__ gs,
    const float* __restrict__ alpha, float* __restrict__ out) {
  const float a = 0.3f / (1.f + __expf(-alpha[0]));
  const size_t i4 = (size_t)blockIdx.x * 256 + threadIdx.x;
  const float4 xv = ((const float4*)x)[i4];
  const float4 g = *(const float4*)&gs[(i4 >> 20) * 1024 + (i4 & 255) * 4];
  float4 o;
  o.x = xv.x + a * g.x; o.y = xv.y + a * g.y;
  o.z = xv.z + a * g.z; o.w = xv.w + a * g.w;
  ((float4*)out)[i4] = o;
}

extern "C" void kernel_launch(void* const* d_in, const int* in_sizes, int n_in,
                              void* d_out, int out_size, void* d_ws, size_t ws_size,
                              hipStream_t stream) {
  const float* prompt = (const float*)d_in[0];
  const float* x      = (const float*)d_in[1];
  const float* lnqw   = (const float*)d_in[2];
  const float* lnqb   = (const float*)d_in[3];
  const float* lnkw   = (const float*)d_in[4];
  const float* lnkb   = (const float*)d_in[5];
  const float* Wq     = (const float*)d_in[6];
  const float* bq     = (const float*)d_in[7];
  const float* Wk     = (const float*)d_in[8];
  const float* bk     = (const float*)d_in[9];
  const float* Wo     = (const float*)d_in[10];
  const float* bo     = (const float*)d_in[11];
  const float* alpha  = (const float*)d_in[12];
  float* out = (float*)d_out;

  char* ws = (char*)d_ws;
  // kln and Vbf share the first 64 MB: kln fully consumed by the K-GEMM
  // before vtrans_kernel overwrites the region (stream-ordered).
  unsigned short* kln = (unsigned short*)(ws + 0);            // 64 MB
  unsigned short* Vbf = (unsigned short*)(ws + 0);            // 64 MB (after)
  unsigned short* qln = (unsigned short*)(ws + 67108864);     // 4 MB
  unsigned short* Wqb = (unsigned short*)(ws + 71303168);     // 2 MB
  unsigned short* Wkb = (unsigned short*)(ws + 73400320);     // 2 MB
  unsigned short* Qp  = (unsigned short*)(ws + 75497472);     // 4 MB
  float* lpart        = (float*)(ws + 79691776);              // 1 MB
  float* ho           = (float*)(ws + 80740352);              // 32 KB
  float* gs           = (float*)(ws + 80773120);              // 32 KB

  // d_out scratch: Kp (64 MB) + Onum bf16 (33.5 MB); both consumed before
  // final_add_kernel overwrites d_out.
  char* ob = (char*)d_out;
  unsigned short* Kp   = (unsigned short*)(ob + 0);           // 64 MB
  unsigned short* Onum = (unsigned short*)(ob + 67108864);    // 33.5 MB

  ln_bf16_kernel<<<32768, 256, 0, stream>>>(x, lnkw, lnkb, kln);
  ln_bf16_kernel<<<2048, 256, 0, stream>>>(prompt, lnqw, lnqb, qln);
  conv_bf16_kernel<<<1024, 256, 0, stream>>>(Wq, Wqb);
  conv_bf16_kernel<<<1024, 256, 0, stream>>>(Wk, Wkb);
  gemm_bt_kernel<<<dim3(16, 8), 256, 0, stream>>>(qln, Wqb, bq, Qp, 2048);
  gemm_bt_kernel<<<dim3(256, 8), 256, 0, stream>>>(kln, Wkb, bk, Kp, 32768);
  vtrans_kernel<<<dim3(128, 16), 256, 0, stream>>>(x, Vbf);
  attn_kernel<<<dim3(128, NS), 256, 0, stream>>>(Qp, Kp, Vbf, Onum, lpart);
  reduce_heads_kernel<<<128, 256, 0, stream>>>(Onum, lpart, ho);
  wo_proj_kernel<<<32, 256, 0, stream>>>(ho, Wo, bo, gs);
  final_add_kernel<<<32768, 256, 0, stream>>>(x, gs, alpha, out);
}